// Round 9
// baseline (47.565 us; speedup 1.0000x reference)
//
#include <hip/hip_runtime.h>
#include <hip/hip_bf16.h>

#define T_SEQ 1024
#define D_MODEL 256

typedef __attribute__((ext_vector_type(8))) short s16x8;
typedef __attribute__((ext_vector_type(4))) float f32x4v;

__device__ __forceinline__ unsigned short f2bf(float x) {
    union { float f; unsigned int u; } v; v.f = x;
    unsigned int r = v.u + 0x7FFFu + ((v.u >> 16) & 1u);
    return (unsigned short)(r >> 16);
}

__device__ __forceinline__ s16x8 pack8(float4 a, float4 b) {
    union { s16x8 v; unsigned int u[4]; } r;
    union { __hip_bfloat162 h; unsigned int u; } t;
    t.h = __float22bfloat162_rn(make_float2(a.x, a.y)); r.u[0] = t.u;
    t.h = __float22bfloat162_rn(make_float2(a.z, a.w)); r.u[1] = t.u;
    t.h = __float22bfloat162_rn(make_float2(b.x, b.y)); r.u[2] = t.u;
    t.h = __float22bfloat162_rn(make_float2(b.z, b.w)); r.u[3] = t.u;
    return r.v;
}

// LDS map (dynamic, 76032 B). xs is dead after the QKV MFMA phase; ks/vT/qs
// alias its space (written only after barrier 2).
//   [0,      59136) xs[112][264] bf16   (x-tile staging)
//   [0,      16128) ks[112][72]  bf16   (aliases xs)
//   [16128,  33536) vT[64][136]  bf16   (aliases xs)
//   [33536,  40448) qs[48][72]   bf16   (aliases xs)
//   [59136,  76032) S [32][132]  f32
#define SMEM_BYTES 76032

// one block per (b, h, 32-query tile): grid (32,4,4), 256 threads = 4 waves
__global__ __launch_bounds__(256) void xattn(
    const float* __restrict__ x,
    const float* __restrict__ Wq, const float* __restrict__ bq,
    const float* __restrict__ Wk, const float* __restrict__ bk,
    const float* __restrict__ Wv, const float* __restrict__ bv,
    const float* __restrict__ shift_logits, const float* __restrict__ alibi_slope,
    unsigned short* __restrict__ ctxb)
{
    extern __shared__ char smem[];
    unsigned short (*xs)[264] = (unsigned short(*)[264])smem;
    unsigned short (*ks)[72]  = (unsigned short(*)[72])smem;
    unsigned short (*vT)[136] = (unsigned short(*)[136])(smem + 16128);
    unsigned short (*qs)[72]  = (unsigned short(*)[72])(smem + 33536);
    float (*S)[132]           = (float(*)[132])(smem + 59136);

    const int tid  = threadIdx.x;
    const int lane = tid & 63;
    const int w    = tid >> 6;          // wave 0..3
    const int l15  = lane & 15, hi = lane >> 4;
    const int t0 = blockIdx.x * 32;
    const int h  = blockIdx.y;
    const int b  = blockIdx.z;
    const int jbase = t0 - 12;

    // ---- T14 early: W B-frags (3 mats x 8 kt) into regs; biases; head scalars ----
    const int wcol = h * 64 + w * 16 + l15;   // this lane's output column
    float bias_q = bq[wcol], bias_k = bk[wcol], bias_v = bv[wcol];
    float l0 = shift_logits[h * 4 + 0], l1 = shift_logits[h * 4 + 1];
    float l2 = shift_logits[h * 4 + 2], l3 = shift_logits[h * 4 + 3];
    float slope = alibi_slope[h];

    s16x8 bfq[8], bfk[8], bfv[8];
    #pragma unroll
    for (int kt = 0; kt < 8; ++kt) {
        const float* pq = Wq + (size_t)wcol * D_MODEL + kt * 32 + hi * 8;
        const float* pk = Wk + (size_t)wcol * D_MODEL + kt * 32 + hi * 8;
        const float* pv = Wv + (size_t)wcol * D_MODEL + kt * 32 + hi * 8;
        bfq[kt] = pack8(*(const float4*)pq, *(const float4*)(pq + 4));
        bfk[kt] = pack8(*(const float4*)pk, *(const float4*)(pk + 4));
        bfv[kt] = pack8(*(const float4*)pv, *(const float4*)(pv + 4));
    }

    // ---- Phase 1: stage x-tile rows [jbase, jbase+112) f32->bf16, zero OOB ----
    #pragma unroll
    for (int u = 0; u < 14; ++u) {
        int i = u * 256 + tid;
        int rr = i >> 5, c8 = i & 31;
        int j = jbase + rr;
        s16x8 v8 = {0, 0, 0, 0, 0, 0, 0, 0};
        if (j >= 0 && j < T_SEQ) {
            const float* p = x + ((size_t)(b * T_SEQ + j)) * D_MODEL + c8 * 8;
            v8 = pack8(*(const float4*)p, *(const float4*)(p + 4));
        }
        *(s16x8*)&xs[rr][c8 * 8] = v8;
    }
    __syncthreads();   // (1) xs ready

    // ---- Phase 2: QKV GEMM. Wave w owns 16 cols (wcol). 7 row-strips k/v, 3 q. ----
    f32x4v aq[3] = {}, ak[7] = {}, av[7] = {};
    #pragma unroll
    for (int kt = 0; kt < 8; ++kt) {
        s16x8 af[7];
        #pragma unroll
        for (int s = 0; s < 7; ++s)
            af[s] = *(const s16x8*)&xs[s * 16 + l15][kt * 32 + hi * 8];
        #pragma unroll
        for (int s = 0; s < 7; ++s) {
            ak[s] = __builtin_amdgcn_mfma_f32_16x16x32_bf16(af[s], bfk[kt], ak[s], 0, 0, 0);
            av[s] = __builtin_amdgcn_mfma_f32_16x16x32_bf16(af[s], bfv[kt], av[s], 0, 0, 0);
            if (s < 3)
                aq[s] = __builtin_amdgcn_mfma_f32_16x16x32_bf16(af[s], bfq[kt], aq[s], 0, 0, 0);
        }
    }
    __syncthreads();   // (2) all xs reads done; safe to alias

    // ---- Phase 3: scatter k/v/q into attention layouts (aliasing xs) ----
    #pragma unroll
    for (int s = 0; s < 7; ++s) {
        int srow = s * 16 + hi * 4;
        int j0 = jbase + srow;
        #pragma unroll
        for (int r = 0; r < 4; ++r) {
            int j = j0 + r;
            ks[srow + r][w * 16 + l15] =
                (j >= 0 && j < T_SEQ) ? f2bf(ak[s][r] + bias_k) : (unsigned short)0;
        }
        // j0 is 4-aligned and boundaries are multiples of 4 -> group-uniform validity
        bool gv = (j0 >= 0 && j0 < T_SEQ);
        union { ushort4 u4; unsigned short e[4]; } sv;
        #pragma unroll
        for (int r = 0; r < 4; ++r)
            sv.e[r] = gv ? f2bf(av[s][r] + bias_v) : (unsigned short)0;
        *(ushort4*)&vT[w * 16 + l15][srow] = sv.u4;
    }
    #pragma unroll
    for (int s = 0; s < 3; ++s) {
        int srow = s * 16 + hi * 4;
        #pragma unroll
        for (int r = 0; r < 4; ++r)
            qs[srow + r][w * 16 + l15] = f2bf((aq[s][r] + bias_q) * 0.125f);
    }
    // zero vT tail cols [112,128) so PV's 0*garbage can't NaN (256 thr = exact)
    {
        int d = tid >> 2, c4 = (tid & 3) * 4;
        ushort4 z = {0, 0, 0, 0};
        *(ushort4*)&vT[d][112 + c4] = z;
    }
    __syncthreads();   // (3) ks/vT/qs ready

    // ---- Phase 4: QK^T (32 x 112, K=64); 14 units over 4 waves ----
    {
        const int rs = w & 1;
        s16x8 aq0 = *(const s16x8*)&qs[12 + rs * 16 + l15][hi * 8];
        s16x8 aq1 = *(const s16x8*)&qs[12 + rs * 16 + l15][32 + hi * 8];
        for (int u = w; u < 14; u += 4) {
            int cf = u >> 1;     // u&1 == w&1 == rs
            s16x8 b0 = *(const s16x8*)&ks[cf * 16 + l15][hi * 8];
            s16x8 b1 = *(const s16x8*)&ks[cf * 16 + l15][32 + hi * 8];
            f32x4v acc = {};
            acc = __builtin_amdgcn_mfma_f32_16x16x32_bf16(aq0, b0, acc, 0, 0, 0);
            acc = __builtin_amdgcn_mfma_f32_16x16x32_bf16(aq1, b1, acc, 0, 0, 0);
            #pragma unroll
            for (int r = 0; r < 4; ++r)
                S[rs * 16 + hi * 4 + r][cf * 16 + l15] = acc[r];
        }
    }
    __syncthreads();   // (4) S ready

    // ---- Phase 5: window softmax (8 threads/query) + in-place P2 ----
    {
        float mx = fmaxf(fmaxf(l0, l1), fmaxf(l2, l3));
        float s0 = __expf(l0 - mx), s1 = __expf(l1 - mx), s2 = __expf(l2 - mx), s3 = __expf(l3 - mx);
        float inv = 1.0f / (s0 + s1 + s2 + s3);
        float pi0 = s0 * inv + 1e-8f, pi1 = s1 * inv + 1e-8f;
        float pi2 = s2 * inv + 1e-8f, pi3 = s3 * inv + 1e-8f;

        const int tq = tid >> 3;     // query row 0..31
        const int g  = tid & 7;
        const int tg = t0 + tq;
        float att[8];
        #pragma unroll
        for (int u = 0; u < 8; ++u) {
            int o = g + 8 * u;
            int k = tg + o;
            if (k < T_SEQ) {
                int r0 = tq + o + 12;
                float z = pi0 * __expf(S[tq][r0])     + pi1 * __expf(S[tq][r0 - 4])
                        + pi2 * __expf(S[tq][r0 - 8]) + pi3 * __expf(S[tq][r0 - 12]);
                att[u] = __logf(z) - slope * (float)o;
            } else att[u] = -1e30f;
        }
        float m = att[0];
        #pragma unroll
        for (int u = 1; u < 8; ++u) m = fmaxf(m, att[u]);
        m = fmaxf(m, __shfl_xor(m, 1));
        m = fmaxf(m, __shfl_xor(m, 2));
        m = fmaxf(m, __shfl_xor(m, 4));
        float Zs = 0.0f;
        #pragma unroll
        for (int u = 0; u < 8; ++u) { att[u] = __expf(att[u] - m); Zs += att[u]; }
        Zs += __shfl_xor(Zs, 1);
        Zs += __shfl_xor(Zs, 2);
        Zs += __shfl_xor(Zs, 4);
        float rz = 1.0f / Zs;

        // p into slot (k - jbase); zero edges [tq,tq+12) U [tq+76,tq+88)
        #pragma unroll
        for (int u = 0; u < 8; ++u) S[tq][tq + g + 8 * u + 12] = att[u] * rz;
        for (int i = g; i < 24; i += 8) {
            int slot = tq + (i < 12 ? i : i + 64);
            S[tq][slot] = 0.0f;
        }
        // in-place P2 over K=128; ascending rj, 8 writers/row in one wave (lockstep-safe)
        for (int rj = g; rj < 128; rj += 8) {
            float val = 0.0f;
            if (rj >= tq && rj <= tq + 75)
                val = S[tq][rj] + S[tq][rj + 4] + S[tq][rj + 8] + S[tq][rj + 12];
            S[tq][rj] = val;
        }
    }
    __syncthreads();   // (5) P2 ready

    // ---- Phase 6: PV (32 x 64, K=128); wave w -> col-frag w ----
    #pragma unroll
    for (int rr = 0; rr < 2; ++rr) {
        s16x8 ap[4];
        #pragma unroll
        for (int kt = 0; kt < 4; ++kt) {
            const float* sp = &S[rr * 16 + l15][kt * 32 + hi * 8];
            ap[kt] = pack8(*(const float4*)sp, *(const float4*)(sp + 4));
        }
        f32x4v acc = {};
        #pragma unroll
        for (int kt = 0; kt < 4; ++kt)
            acc = __builtin_amdgcn_mfma_f32_16x16x32_bf16(
                ap[kt], *(const s16x8*)&vT[w * 16 + l15][kt * 32 + hi * 8], acc, 0, 0, 0);
        #pragma unroll
        for (int r = 0; r < 4; ++r) {
            int row = t0 + rr * 16 + hi * 4 + r;
            ctxb[(size_t)(b * T_SEQ + row) * D_MODEL + h * 64 + w * 16 + l15] = f2bf(acc[r]);
        }
    }
}

// ---- O GEMM: out = ctx @ Wo^T + bo (f32 out); Wo cvt'd in-register (R2-proven) ----
__global__ __launch_bounds__(256) void gemm_o(
    const unsigned short* __restrict__ ctxb, const float* __restrict__ Wo,
    const float* __restrict__ bo, float* __restrict__ out)
{
    const int lane = threadIdx.x & 63;
    const int w    = threadIdx.x >> 6;
    const int l15  = lane & 15, hi = lane >> 4;
    const int row0 = blockIdx.x * 64;
    const int col0 = blockIdx.y * 64;

    const unsigned short* Ap = ctxb + (size_t)(row0 + w * 16 + l15) * D_MODEL;
    s16x8 ao[8];
    #pragma unroll
    for (int kt = 0; kt < 8; ++kt)
        ao[kt] = *(const s16x8*)(Ap + kt * 32 + hi * 8);

    f32x4v acc[4] = {};
    #pragma unroll
    for (int kt = 0; kt < 8; ++kt) {
        int koff = kt * 32 + hi * 8;
        #pragma unroll
        for (int c = 0; c < 4; ++c) {
            const float* Bp = Wo + (size_t)(col0 + c * 16 + l15) * D_MODEL + koff;
            acc[c] = __builtin_amdgcn_mfma_f32_16x16x32_bf16(
                ao[kt], pack8(*(const float4*)Bp, *(const float4*)(Bp + 4)), acc[c], 0, 0, 0);
        }
    }
    #pragma unroll
    for (int c = 0; c < 4; ++c) {
        int col = col0 + c * 16 + l15;
        float bs = bo[col];
        #pragma unroll
        for (int r = 0; r < 4; ++r) {
            int row = row0 + w * 16 + hi * 4 + r;
            out[(size_t)row * D_MODEL + col] = acc[c][r] + bs;
        }
    }
}

extern "C" void kernel_launch(void* const* d_in, const int* in_sizes, int n_in,
                              void* d_out, int out_size, void* d_ws, size_t ws_size,
                              hipStream_t stream) {
    const float* x  = (const float*)d_in[0];
    const float* Wq = (const float*)d_in[1];
    const float* bq = (const float*)d_in[2];
    const float* Wk = (const float*)d_in[3];
    const float* bk = (const float*)d_in[4];
    const float* Wv = (const float*)d_in[5];
    const float* bv = (const float*)d_in[6];
    const float* Wo = (const float*)d_in[7];
    const float* bo = (const float*)d_in[8];
    const float* shift_logits = (const float*)d_in[9];
    const float* alibi_slope  = (const float*)d_in[10];
    float* out = (float*)d_out;

    unsigned short* ctx = (unsigned short*)d_ws;   // 4096 x 256 bf16 = 2 MB

    hipFuncSetAttribute(reinterpret_cast<const void*>(xattn),
                        hipFuncAttributeMaxDynamicSharedMemorySize, SMEM_BYTES);

    xattn<<<dim3(32, 4, 4), dim3(256), SMEM_BYTES, stream>>>(
        x, Wq, bq, Wk, bk, Wv, bv, shift_logits, alibi_slope, ctx);
    gemm_o<<<dim3(64, 4), dim3(256), 0, stream>>>(ctx, Wo, bo, out);
}

// Round 10
// 33.494 us; speedup vs baseline: 1.4201x; 1.4201x over previous
//
#include <hip/hip_runtime.h>
#include <hip/hip_bf16.h>

#define T_SEQ 1024
#define D_MODEL 256
#define VBT_W 1152   // 12 front guard + 1024 + 116 back guard

typedef __attribute__((ext_vector_type(8))) short s16x8;
typedef __attribute__((ext_vector_type(4))) float f32x4v;

__device__ __forceinline__ unsigned short f2bf(float x) {
    union { float f; unsigned int u; } v; v.f = x;
    unsigned int r = v.u + 0x7FFFu + ((v.u >> 16) & 1u);
    return (unsigned short)(r >> 16);
}

__device__ __forceinline__ s16x8 pack8(float4 a, float4 b) {
    union { s16x8 v; unsigned int u[4]; } r;
    union { __hip_bfloat162 h; unsigned int u; } t;
    t.h = __float22bfloat162_rn(make_float2(a.x, a.y)); r.u[0] = t.u;
    t.h = __float22bfloat162_rn(make_float2(a.z, a.w)); r.u[1] = t.u;
    t.h = __float22bfloat162_rn(make_float2(b.x, b.y)); r.u[2] = t.u;
    t.h = __float22bfloat162_rn(make_float2(b.z, b.w)); r.u[3] = t.u;
    return r.v;
}

// ---- QKV GEMM + V-transpose + Wo cvt + guard zeroing (R6 verbatim; bx-fast
// grid makes each 64-row output stripe XCD-local: XCD = bx % 8) ----
__global__ __launch_bounds__(256) void qkv_prep(
    const float* __restrict__ x,
    const float* __restrict__ Wq, const float* __restrict__ bq,
    const float* __restrict__ Wk, const float* __restrict__ bk,
    const float* __restrict__ Wv, const float* __restrict__ bv,
    const float* __restrict__ Wo,
    unsigned short* __restrict__ qb, unsigned short* __restrict__ kb,
    unsigned short* __restrict__ vbT, unsigned short* __restrict__ wob)
{
    __shared__ unsigned short Bl[64][264];

    const int tid  = threadIdx.x;
    const int lane = tid & 63;
    const int w    = tid >> 6;
    const int l15  = lane & 15, hi = lane >> 4;
    const int row0 = blockIdx.x * 64;
    const int mat  = blockIdx.y >> 2;
    const int col0 = (blockIdx.y & 3) * 64;
    const int fid  = blockIdx.y * 64 + blockIdx.x;

    const float* W    = (mat == 0) ? Wq : (mat == 1) ? Wk : Wv;
    const float* bias = (mat == 0) ? bq : (mat == 1) ? bk : bv;

    const int arow = row0 + w * 16 + l15;
    const float* Ap = x + (size_t)arow * D_MODEL;
    float4 a4[16];
    #pragma unroll
    for (int kt = 0; kt < 8; ++kt) {
        a4[2 * kt]     = *(const float4*)(Ap + kt * 32 + hi * 8);
        a4[2 * kt + 1] = *(const float4*)(Ap + kt * 32 + hi * 8 + 4);
    }

    for (int i = tid; i < 2048; i += 256) {
        int r = i >> 5, c8 = i & 31;
        const float* p = W + (size_t)(col0 + r) * D_MODEL + c8 * 8;
        *(s16x8*)&Bl[r][c8 * 8] = pack8(*(const float4*)p, *(const float4*)(p + 4));
    }
    __syncthreads();

    f32x4v acc[4] = {};
    #pragma unroll
    for (int kt = 0; kt < 8; ++kt) {
        int koff = kt * 32 + hi * 8;
        s16x8 a = pack8(a4[2 * kt], a4[2 * kt + 1]);
        #pragma unroll
        for (int c = 0; c < 4; ++c)
            acc[c] = __builtin_amdgcn_mfma_f32_16x16x32_bf16(a, *(const s16x8*)&Bl[c * 16 + l15][koff], acc[c], 0, 0, 0);
    }
    if (mat == 2) {
        int bq4 = row0 >> 10;
        int j0  = (row0 & 1023) + w * 16 + hi * 4;
        #pragma unroll
        for (int c = 0; c < 4; ++c) {
            int col = col0 + c * 16 + l15;
            int hh = col >> 6, dh = col & 63;
            float bs = bias[col];
            union { ushort4 u4; unsigned short s[4]; } st;
            #pragma unroll
            for (int r = 0; r < 4; ++r) st.s[r] = f2bf(acc[c][r] + bs);
            *(ushort4*)(vbT + (size_t)((bq4 * 4 + hh) * 64 + dh) * VBT_W + 12 + j0) = st.u4;
        }
    } else {
        unsigned short* o = (mat == 0) ? qb : kb;
        float sc = (mat == 0) ? 0.125f : 1.0f;
        #pragma unroll
        for (int c = 0; c < 4; ++c) {
            int col = col0 + c * 16 + l15;
            float bs = bias[col];
            #pragma unroll
            for (int r = 0; r < 4; ++r) {
                int row = row0 + w * 16 + hi * 4 + r;
                o[(size_t)row * D_MODEL + col] = f2bf((acc[c][r] + bs) * sc);
            }
        }
    }

    int gid = fid * 256 + tid;
    if (gid < 1024 * 128) {
        int row = gid >> 7, g = gid & 127;
        int colg = (g < 12) ? g : (1024 + g);
        vbT[(size_t)row * VBT_W + colg] = 0;
    }
    if (gid < 8192) {
        const float* p = Wo + gid * 8;
        *(s16x8*)(wob + gid * 8) = pack8(*(const float4*)p, *(const float4*)(p + 4));
    }
}

// ---- attention: 1024 one-wave blocks, one (b,h,16-row tile) per wave ----
// No multi-wave sync. XCD-swizzled so reads are L2-local to qkv_prep's writes.
__global__ __launch_bounds__(64) void attn(
    const unsigned short* __restrict__ qb, const unsigned short* __restrict__ kb,
    const unsigned short* __restrict__ vbT,
    const float* __restrict__ shift_logits, const float* __restrict__ alibi_slope,
    unsigned short* __restrict__ ctxb)
{
    __shared__ float S[16][108];   // 6912 B, wave-private

    const int lane = threadIdx.x;
    const int l15  = lane & 15, hi = lane >> 4;

    // decode with XCD alignment: bid%8 == (t0/64)%8
    const int n  = blockIdx.x;
    const int x7 = n & 7;
    const int i  = n >> 3;
    const int tl = i & 3;
    const int sh = (i >> 2) & 1;
    const int h  = (i >> 3) & 3;
    const int b  = i >> 5;
    const int s_ = x7 + 8 * sh;          // 64-row stripe 0..15
    const int t0 = (4 * s_ + tl) * 16;   // query tile start
    const int jbase = t0 - 12;

    // ---- T14: all global loads issued up front ----
    const unsigned short* qrow = qb + (size_t)(b * T_SEQ + t0 + l15) * D_MODEL + h * 64;
    s16x8 aq0 = *(const s16x8*)(qrow + hi * 8);
    s16x8 aq1 = *(const s16x8*)(qrow + 32 + hi * 8);

    s16x8 bk0[6], bk1[6];
    #pragma unroll
    for (int cf = 0; cf < 6; ++cf) {
        int j = jbase + cf * 16 + l15;
        s16x8 z = {0,0,0,0,0,0,0,0};
        bk0[cf] = z; bk1[cf] = z;
        if (j >= 0 && j < T_SEQ) {
            const unsigned short* kr = kb + (size_t)(b * T_SEQ + j) * D_MODEL + h * 64;
            bk0[cf] = *(const s16x8*)(kr + hi * 8);
            bk1[cf] = *(const s16x8*)(kr + 32 + hi * 8);
        }
    }
    s16x8 bv[4][3];
    #pragma unroll
    for (int c = 0; c < 4; ++c) {
        const unsigned short* vrow =
            vbT + (size_t)((b * 4 + h) * 64 + c * 16 + l15) * VBT_W + t0;
        #pragma unroll
        for (int kt = 0; kt < 3; ++kt)
            bv[c][kt] = *(const s16x8*)(vrow + kt * 32 + hi * 8);
    }
    float l0 = shift_logits[h * 4 + 0], l1 = shift_logits[h * 4 + 1];
    float l2 = shift_logits[h * 4 + 2], l3 = shift_logits[h * 4 + 3];
    float slope = alibi_slope[h];

    // ---- QK^T: S(16x96) = q . k^T, K=64 ----
    #pragma unroll
    for (int cf = 0; cf < 6; ++cf) {
        f32x4v acc = {};
        acc = __builtin_amdgcn_mfma_f32_16x16x32_bf16(aq0, bk0[cf], acc, 0, 0, 0);
        acc = __builtin_amdgcn_mfma_f32_16x16x32_bf16(aq1, bk1[cf], acc, 0, 0, 0);
        #pragma unroll
        for (int r = 0; r < 4; ++r)
            S[hi * 4 + r][cf * 16 + l15] = acc[r];
    }
    __syncthreads();   // single-wave: just an LDS ordering point

    // ---- window softmax: row = l15, 4 lanes/row (g = hi) ----
    {
        float mx = fmaxf(fmaxf(l0, l1), fmaxf(l2, l3));
        float s0 = __expf(l0 - mx), s1 = __expf(l1 - mx), s2 = __expf(l2 - mx), s3 = __expf(l3 - mx);
        float inv = 1.0f / (s0 + s1 + s2 + s3);
        float pi0 = s0 * inv + 1e-8f, pi1 = s1 * inv + 1e-8f;
        float pi2 = s2 * inv + 1e-8f, pi3 = s3 * inv + 1e-8f;

        const int tq = l15;
        const int g  = hi;
        const int tg = t0 + tq;
        float att[16];
        #pragma unroll
        for (int u = 0; u < 16; ++u) {
            int o = g + 4 * u;
            int k = tg + o;
            if (k < T_SEQ) {
                int r0 = tq + o + 12;
                float z = pi0 * __expf(S[tq][r0])     + pi1 * __expf(S[tq][r0 - 4])
                        + pi2 * __expf(S[tq][r0 - 8]) + pi3 * __expf(S[tq][r0 - 12]);
                att[u] = __logf(z) - slope * (float)o;
            } else att[u] = -1e30f;
        }
        float m = att[0];
        #pragma unroll
        for (int u = 1; u < 16; ++u) m = fmaxf(m, att[u]);
        m = fmaxf(m, __shfl_xor(m, 16));
        m = fmaxf(m, __shfl_xor(m, 32));
        float Zs = 0.0f;
        #pragma unroll
        for (int u = 0; u < 16; ++u) { att[u] = __expf(att[u] - m); Zs += att[u]; }
        Zs += __shfl_xor(Zs, 16);
        Zs += __shfl_xor(Zs, 32);
        float rz = 1.0f / Zs;

        // p into slot (k - jbase) = tq+o+12; zero edges [tq,tq+12) U [tq+76,tq+88)
        #pragma unroll
        for (int u = 0; u < 16; ++u) S[tq][tq + g + 4 * u + 12] = att[u] * rz;
        #pragma unroll
        for (int e = g; e < 24; e += 4) {
            int slot = tq + (e < 12 ? e : e + 64);
            S[tq][slot] = 0.0f;
        }
        // in-place P2: stride-4 residue classes -> each lane reads only its own
        // future writes (no cross-lane hazard); ascending rj
        #pragma unroll
        for (int ii = 0; ii < 24; ++ii) {
            int rj = g + 4 * ii;
            float val = 0.0f;
            if (rj >= tq && rj <= tq + 75)
                val = S[tq][rj] + S[tq][rj + 4] + S[tq][rj + 8] + S[tq][rj + 12];
            S[tq][rj] = val;
        }
    }
    __syncthreads();   // LDS ordering before fragment reads

    // ---- PV: ctx(16x64) = P2 @ vbT, K=96 ----
    {
        s16x8 ap[3];
        #pragma unroll
        for (int kt = 0; kt < 3; ++kt) {
            const float* sp = &S[l15][kt * 32 + hi * 8];
            ap[kt] = pack8(*(const float4*)sp, *(const float4*)(sp + 4));
        }
        #pragma unroll
        for (int c = 0; c < 4; ++c) {
            f32x4v acc = {};
            #pragma unroll
            for (int kt = 0; kt < 3; ++kt)
                acc = __builtin_amdgcn_mfma_f32_16x16x32_bf16(ap[kt], bv[c][kt], acc, 0, 0, 0);
            #pragma unroll
            for (int r = 0; r < 4; ++r) {
                int row = t0 + hi * 4 + r;
                ctxb[(size_t)(b * T_SEQ + row) * D_MODEL + h * 64 + c * 16 + l15] = f2bf(acc[r]);
            }
        }
    }
}

// ---- O GEMM: out = ctx @ wob^T + bo (f32 out); B direct from bf16 wob ----
__global__ __launch_bounds__(256) void gemm_o(
    const unsigned short* __restrict__ ctxb, const unsigned short* __restrict__ wob,
    const float* __restrict__ bo, float* __restrict__ out)
{
    const int lane = threadIdx.x & 63;
    const int w    = threadIdx.x >> 6;
    const int l15  = lane & 15, hi = lane >> 4;
    const int row0 = blockIdx.x * 64;
    const int col0 = blockIdx.y * 64;

    const unsigned short* Ap = ctxb + (size_t)(row0 + w * 16 + l15) * D_MODEL;
    s16x8 ao[8];
    #pragma unroll
    for (int kt = 0; kt < 8; ++kt)
        ao[kt] = *(const s16x8*)(Ap + kt * 32 + hi * 8);

    f32x4v acc[4] = {};
    #pragma unroll
    for (int kt = 0; kt < 8; ++kt) {
        int koff = kt * 32 + hi * 8;
        #pragma unroll
        for (int c = 0; c < 4; ++c)
            acc[c] = __builtin_amdgcn_mfma_f32_16x16x32_bf16(
                ao[kt], *(const s16x8*)(wob + (size_t)(col0 + c * 16 + l15) * D_MODEL + koff), acc[c], 0, 0, 0);
    }
    #pragma unroll
    for (int c = 0; c < 4; ++c) {
        int col = col0 + c * 16 + l15;
        float bs = bo[col];
        #pragma unroll
        for (int r = 0; r < 4; ++r) {
            int row = row0 + w * 16 + hi * 4 + r;
            out[(size_t)row * D_MODEL + col] = acc[c][r] + bs;
        }
    }
}

extern "C" void kernel_launch(void* const* d_in, const int* in_sizes, int n_in,
                              void* d_out, int out_size, void* d_ws, size_t ws_size,
                              hipStream_t stream) {
    const float* x  = (const float*)d_in[0];
    const float* Wq = (const float*)d_in[1];
    const float* bq = (const float*)d_in[2];
    const float* Wk = (const float*)d_in[3];
    const float* bk = (const float*)d_in[4];
    const float* Wv = (const float*)d_in[5];
    const float* bv = (const float*)d_in[6];
    const float* Wo = (const float*)d_in[7];
    const float* bo = (const float*)d_in[8];
    const float* shift_logits = (const float*)d_in[9];
    const float* alibi_slope  = (const float*)d_in[10];
    float* out = (float*)d_out;

    char* ws = (char*)d_ws;
    unsigned short* qb  = (unsigned short*)(ws);                 // 2 MB
    unsigned short* kb  = (unsigned short*)(ws + (2u << 20));    // 2 MB
    unsigned short* vbT = (unsigned short*)(ws + (4u << 20));    // 2.25 MB
    unsigned short* wob = (unsigned short*)(ws + (7u << 20));    // 128 KB
    unsigned short* ctx = (unsigned short*)(ws + (8u << 20));    // 2 MB

    qkv_prep<<<dim3(64, 12), dim3(256), 0, stream>>>(
        x, Wq, bq, Wk, bk, Wv, bv, Wo, qb, kb, vbT, wob);
    attn<<<dim3(1024), dim3(64), 0, stream>>>(
        qb, kb, vbT, shift_logits, alibi_slope, ctx);
    gemm_o<<<dim3(64, 4), dim3(256), 0, stream>>>(ctx, wob, bo, out);
}